// Round 1
// baseline (5014.894 us; speedup 1.0000x reference)
//
#include <hip/hip_runtime.h>

// NeRV splat: trilinear scatter of per-point features into 256^3 volumes,
// with the per-group view-mean fused into the splat weight.
// views 0,1 -> out volume 0 (weight 0.5 each); view 2 -> out volume 1 (weight 1.0).

#define V 256
#define VOLSZ (V * V * V)          // 16,777,216
#define LOG2P 22                   // P = 64*256*256 = 2^22
#define NPTS (3 << LOG2P)          // 12,582,912 total points

__global__ __launch_bounds__(256)
void zero_f4(float4* __restrict__ p, int n4) {
    int i = blockIdx.x * blockDim.x + threadIdx.x;
    if (i < n4) p[i] = make_float4(0.f, 0.f, 0.f, 0.f);
}

__global__ __launch_bounds__(256)
void splat(const float* __restrict__ pts,
           const float* __restrict__ feat,
           float* __restrict__ out)
{
    int i = blockIdx.x * blockDim.x + threadIdx.x;
    if (i >= NPTS) return;

    int b = i >> LOG2P;                       // view index 0..2

    const float* pp = pts + (long long)i * 3; // [B,P,3] flat
    float x = pp[0];
    float y = pp[1];
    float z = pp[2];
    float f = feat[i];                        // [B,P,1] flat

    // fused group mean: views 0,1 -> group 0 (x0.5); view 2 -> group 1 (x1.0)
    float scale   = (b < 2) ? 0.5f : 1.0f;
    float* dst    = out + ((b < 2) ? 0 : VOLSZ);

    const float s = 127.5f;                   // (V-1)/2, align_corners=True
    float xf = (x + 1.f) * s;
    float yf = (y + 1.f) * s;
    float zf = (z + 1.f) * s;
    float lx = floorf(xf), ly = floorf(yf), lz = floorf(zf);
    float fx = xf - lx,    fy = yf - ly,    fz = zf - lz;
    int ix = (int)lx, iy = (int)ly, iz = (int)lz;

    float wv = f * scale;
    float wx[2] = {1.f - fx, fx};
    float wy[2] = {1.f - fy, fy};
    float wz[2] = {1.f - fz, fz};

#pragma unroll
    for (int dz = 0; dz < 2; ++dz) {
        int z2 = iz + dz;
        if ((unsigned)z2 >= (unsigned)V) continue;   // out-of-range corner has weight 0
#pragma unroll
        for (int dy = 0; dy < 2; ++dy) {
            int y2 = iy + dy;
            if ((unsigned)y2 >= (unsigned)V) continue;
            float wzy = wz[dz] * wy[dy] * wv;
            int base = (z2 * V + y2) * V;
#pragma unroll
            for (int dx = 0; dx < 2; ++dx) {
                int x2 = ix + dx;
                if ((unsigned)x2 >= (unsigned)V) continue;
                // HW global_atomic_add_f32 (device memory is coarse-grained here)
                unsafeAtomicAdd(dst + base + x2, wzy * wx[dx]);
            }
        }
    }
}

extern "C" void kernel_launch(void* const* d_in, const int* in_sizes, int n_in,
                              void* d_out, int out_size, void* d_ws, size_t ws_size,
                              hipStream_t stream) {
    const float* pts  = (const float*)d_in[0];   // [3, 2^22, 3] f32
    const float* feat = (const float*)d_in[1];   // [3, 2^22, 1] f32
    float* out = (float*)d_out;                  // [2,1,256,256,256] f32

    // 1) zero the output (harness poisons it before every launch)
    int n4 = out_size / 4;                       // 8,388,608 float4s
    int zb = (n4 + 255) / 256;
    zero_f4<<<zb, 256, 0, stream>>>((float4*)out, n4);

    // 2) splat all points
    int sb = (NPTS + 255) / 256;                 // 49,152 blocks
    splat<<<sb, 256, 0, stream>>>(pts, feat, out);
}

// Round 2
// 1556.300 us; speedup vs baseline: 3.2223x; 3.2223x over previous
//
#include <hip/hip_runtime.h>

// NeRV trilinear splat, global-atomic-free version.
// Round-1 evidence: scattered f32 global atomics run at ~21 G/s (32 B fabric
// packet each, WRITE_SIZE showed 32 B/atomic) -> 4.8 ms. This version bins
// points into 16^3-voxel cells, aggregates in LDS, and writes the volume with
// plain stores; cell-boundary halos go through a side buffer + gather pass.

#define V 256
#define VOLSZ (V * V * V)              // 16,777,216
#define LOG2P 22
#define NPTS (3 << LOG2P)              // 12,582,912
#define NBLK 512                       // blocks for count/scatter
#define PPB (NPTS / NBLK)              // 24,576 points per block
#define PITER (PPB / 256)              // 96 per thread
#define NBINS 8192                     // 2 groups * 16^3 cells
#define TILE 17
#define TILE2 (TILE * TILE)            // 289
#define TILE3 (TILE * TILE * TILE)     // 4913
#define HALO 817                       // 17^3 - 16^3 boundary positions
#define NCELLS 8192

// workspace layout (bytes)
#define A_OFF 0ULL
#define A_BYTES (8ULL * NPTS)                       // payload A (packed coords)
#define P_OFF (A_OFF + A_BYTES)
#define P_BYTES (4ULL * NBLK * NBINS)               // per-block histograms / offsets
#define T_OFF (P_OFF + P_BYTES)
#define T_BYTES (4ULL * NBINS)                      // bin totals
#define B_OFF (T_OFF + T_BYTES)
#define B_BYTES (4ULL * (NBINS + 1) + 28)           // bases (exclusive scan), padded
#define F_OFF (B_OFF + B_BYTES)
#define F_BYTES (4ULL * NPTS)                       // payload B (weighted feature)
#define H_OFF (F_OFF + F_BYTES)
#define H_BYTES (4ULL * NCELLS * HALO)              // halo side buffer
#define WS_REQ (H_OFF + H_BYTES)                    // ~194.6 MB

// fixed-point: voxel coord * 4096 (12-bit fraction). cell = X>>16, local = X&0xFFFF.
__device__ __forceinline__ void point_to_fixed(float x, float y, float z,
                                               unsigned& X, unsigned& Y, unsigned& Z,
                                               int& cellbin) {
    float xf = (x + 1.f) * 127.5f;   // [0, 255]
    float yf = (y + 1.f) * 127.5f;
    float zf = (z + 1.f) * 127.5f;
    X = (unsigned)(int)(xf * 4096.0f);
    Y = (unsigned)(int)(yf * 4096.0f);
    Z = (unsigned)(int)(zf * 4096.0f);
    int cx = (int)(X >> 16), cy = (int)(Y >> 16), cz = (int)(Z >> 16); // [0,15]
    cellbin = (cz << 8) | (cy << 4) | cx;
}

// ---------------- pass 1: per-block histogram ----------------
__global__ __launch_bounds__(256)
void count_k(const float* __restrict__ pts, unsigned* __restrict__ partials) {
    __shared__ unsigned hist[NBINS];
    for (int j = threadIdx.x; j < NBINS; j += 256) hist[j] = 0u;
    __syncthreads();
    int b = blockIdx.x;
    long long base = (long long)b * PPB;
#pragma unroll 4
    for (int k = 0; k < PITER; ++k) {
        long long i = base + threadIdx.x + k * 256;
        int view = (int)(i >> LOG2P);
        const float* pp = pts + i * 3;
        unsigned X, Y, Z; int cb;
        point_to_fixed(pp[0], pp[1], pp[2], X, Y, Z, cb);
        int bin = ((view < 2) ? 0 : 4096) + cb;
        atomicAdd(&hist[bin], 1u);
    }
    __syncthreads();
    for (int j = threadIdx.x; j < NBINS; j += 256)
        partials[(size_t)b * NBINS + j] = hist[j];
}

// ---------------- pass 2a: bin totals ----------------
__global__ __launch_bounds__(256)
void totals_k(const unsigned* __restrict__ partials, unsigned* __restrict__ totals) {
    int bin = blockIdx.x * 256 + threadIdx.x;
    unsigned s = 0;
#pragma unroll 8
    for (int k = 0; k < NBLK; ++k) s += partials[(size_t)k * NBINS + bin];
    totals[bin] = s;
}

// ---------------- pass 2b: exclusive scan of totals -> bases[8193] ----------------
__global__ __launch_bounds__(1024)
void scan_k(const unsigned* __restrict__ totals, unsigned* __restrict__ bases) {
    __shared__ unsigned chunk[1024];
    int t = threadIdx.x;
    unsigned v[8]; unsigned run = 0;
#pragma unroll
    for (int j = 0; j < 8; ++j) { v[j] = totals[t * 8 + j]; run += v[j]; }
    chunk[t] = run;
    __syncthreads();
    for (int off = 1; off < 1024; off <<= 1) {
        unsigned add = (t >= off) ? chunk[t - off] : 0u;
        __syncthreads();
        chunk[t] += add;
        __syncthreads();
    }
    unsigned excl = (t == 0) ? 0u : chunk[t - 1];
    unsigned r = excl;
    if (t == 0) bases[0] = 0u;
#pragma unroll
    for (int j = 0; j < 8; ++j) { r += v[j]; bases[t * 8 + 1 + j] = r; }
}

// ---------------- pass 2c: per-(block,bin) start offsets, in place ----------------
__global__ __launch_bounds__(256)
void offsets_k(unsigned* __restrict__ partials, const unsigned* __restrict__ bases) {
    int bin = blockIdx.x * 256 + threadIdx.x;
    unsigned run = bases[bin];
#pragma unroll 8
    for (int k = 0; k < NBLK; ++k) {
        unsigned c = partials[(size_t)k * NBINS + bin];
        partials[(size_t)k * NBINS + bin] = run;
        run += c;
    }
}

// ---------------- pass 3: scatter points into bin-sorted payload ----------------
__global__ __launch_bounds__(256)
void scatter_k(const float* __restrict__ pts, const float* __restrict__ feat,
               const unsigned* __restrict__ offsets,
               unsigned long long* __restrict__ payA, float* __restrict__ payB) {
    __shared__ unsigned cur[NBINS];
    int b = blockIdx.x;
    for (int j = threadIdx.x; j < NBINS; j += 256)
        cur[j] = offsets[(size_t)b * NBINS + j];
    __syncthreads();
    long long base = (long long)b * PPB;
#pragma unroll 2
    for (int k = 0; k < PITER; ++k) {
        long long i = base + threadIdx.x + k * 256;
        int view = (int)(i >> LOG2P);
        const float* pp = pts + i * 3;
        unsigned X, Y, Z; int cb;
        point_to_fixed(pp[0], pp[1], pp[2], X, Y, Z, cb);
        int bin = ((view < 2) ? 0 : 4096) + cb;
        float wv = feat[i] * ((view < 2) ? 0.5f : 1.0f);
        unsigned slot = atomicAdd(&cur[bin], 1u);
        unsigned long long lx = X & 0xFFFFu, ly = Y & 0xFFFFu, lz = Z & 0xFFFFu;
        payA[slot] = lx | (ly << 16) | (lz << 32);
        payB[slot] = wv;
    }
}

// ---------------- pass 4: per-cell splat into LDS tile, plain flush ----------------
__global__ __launch_bounds__(256)
void splat_cells_k(const unsigned long long* __restrict__ payA,
                   const float* __restrict__ payB,
                   const unsigned* __restrict__ bases,
                   float* __restrict__ out, float* __restrict__ halo) {
    __shared__ float tile[TILE3];
    for (int j = threadIdx.x; j < TILE3; j += 256) tile[j] = 0.f;
    __syncthreads();
    int bid = blockIdx.x;
    unsigned s = bases[bid], e = bases[bid + 1];
    for (unsigned i = s + threadIdx.x; i < e; i += 256) {
        unsigned long long a = payA[i];
        float w = payB[i];
        unsigned Xl = (unsigned)(a & 0xFFFFu);
        unsigned Yl = (unsigned)((a >> 16) & 0xFFFFu);
        unsigned Zl = (unsigned)((a >> 32) & 0xFFFFu);
        int lx = Xl >> 12, ly = Yl >> 12, lz = Zl >> 12;       // [0,15]
        float fx = (Xl & 4095u) * (1.f / 4096.f);
        float fy = (Yl & 4095u) * (1.f / 4096.f);
        float fz = (Zl & 4095u) * (1.f / 4096.f);
        float wx0 = 1.f - fx, wy0 = 1.f - fy, wz0 = 1.f - fz;
        int t0 = (lz * TILE + ly) * TILE + lx;
        float w00 = w * wz0 * wy0, w01 = w * wz0 * fy;
        float w10 = w * fz * wy0,  w11 = w * fz * fy;
        atomicAdd(&tile[t0],                 w00 * wx0);
        atomicAdd(&tile[t0 + 1],             w00 * fx);
        atomicAdd(&tile[t0 + TILE],          w01 * wx0);
        atomicAdd(&tile[t0 + TILE + 1],      w01 * fx);
        atomicAdd(&tile[t0 + TILE2],         w10 * wx0);
        atomicAdd(&tile[t0 + TILE2 + 1],     w10 * fx);
        atomicAdd(&tile[t0 + TILE2 + TILE],  w11 * wx0);
        atomicAdd(&tile[t0 + TILE2 + TILE + 1], w11 * fx);
    }
    __syncthreads();
    int g = bid >> 12, cc = bid & 4095;
    int cx = cc & 15, cy = (cc >> 4) & 15, cz = cc >> 8;
    int ox = cx * 16, oy = cy * 16, oz = cz * 16;
    size_t obase = (size_t)g * VOLSZ;
    for (int idx = threadIdx.x; idx < TILE3; idx += 256) {
        int pz = idx / TILE2;
        int rem = idx - pz * TILE2;
        int py = rem / TILE;
        int px = rem - py * TILE;
        float val = tile[idx];
        if (px < 16 && py < 16 && pz < 16) {
            out[obase + ((size_t)(oz + pz) * V + (oy + py)) * V + (ox + px)] = val;
        } else {
            int h;
            if (px == 16)      h = py * TILE + pz;
            else if (py == 16) h = 289 + px * TILE + pz;
            else               h = 561 + px * 16 + py;
            halo[(size_t)bid * HALO + h] = val;
        }
    }
}

// ---------------- pass 5: add halo contributions on %16==0 planes ----------------
__device__ __forceinline__ int hidx(int px, int py, int pz) {
    if (px == 16) return py * TILE + pz;
    if (py == 16) return 289 + px * TILE + pz;
    return 561 + px * 16 + py;
}

__global__ __launch_bounds__(256)
void halo_k(const float* __restrict__ halo, float* __restrict__ out) {
    unsigned tid = blockIdx.x * 256 + threadIdx.x;   // 2^25 threads
    unsigned g = tid >> 24;
    unsigned v = tid & 0xFFFFFFu;
    int vx = v & 255, vy = (v >> 8) & 255, vz = v >> 16;
    int lx = vx & 15, ly = vy & 15, lz = vz & 15;
    int cx = vx >> 4, cy = vy >> 4, cz = vz >> 4;
    bool ax = (lx == 0) && (cx > 0);
    bool ay = (ly == 0) && (cy > 0);
    bool az = (lz == 0) && (cz > 0);
    if (!(ax || ay || az)) return;
    size_t gb = (size_t)(g << 12) * HALO;
    auto cellBase = [&](int ccx, int ccy, int ccz) {
        return gb + (size_t)((ccz << 8) | (ccy << 4) | ccx) * HALO;
    };
    float acc = 0.f;
    if (ax)             acc += halo[cellBase(cx - 1, cy, cz) + hidx(16, ly, lz)];
    if (ay)             acc += halo[cellBase(cx, cy - 1, cz) + hidx(lx, 16, lz)];
    if (az)             acc += halo[cellBase(cx, cy, cz - 1) + hidx(lx, ly, 16)];
    if (ax && ay)       acc += halo[cellBase(cx - 1, cy - 1, cz) + hidx(16, 16, lz)];
    if (ax && az)       acc += halo[cellBase(cx - 1, cy, cz - 1) + hidx(16, ly, 16)];
    if (ay && az)       acc += halo[cellBase(cx, cy - 1, cz - 1) + hidx(lx, 16, 16)];
    if (ax && ay && az) acc += halo[cellBase(cx - 1, cy - 1, cz - 1) + hidx(16, 16, 16)];
    out[(size_t)g * VOLSZ + v] += acc;
}

// ---------------- fallback (ws too small): round-1 direct atomic path ----------------
__global__ __launch_bounds__(256)
void zero_f4(float4* __restrict__ p, int n4) {
    int i = blockIdx.x * blockDim.x + threadIdx.x;
    if (i < n4) p[i] = make_float4(0.f, 0.f, 0.f, 0.f);
}

__global__ __launch_bounds__(256)
void splat_direct(const float* __restrict__ pts, const float* __restrict__ feat,
                  float* __restrict__ out) {
    int i = blockIdx.x * blockDim.x + threadIdx.x;
    if (i >= NPTS) return;
    int b = i >> LOG2P;
    const float* pp = pts + (long long)i * 3;
    float scale = (b < 2) ? 0.5f : 1.0f;
    float* dst = out + ((b < 2) ? 0 : VOLSZ);
    float xf = (pp[0] + 1.f) * 127.5f, yf = (pp[1] + 1.f) * 127.5f, zf = (pp[2] + 1.f) * 127.5f;
    float lxf = floorf(xf), lyf = floorf(yf), lzf = floorf(zf);
    float fx = xf - lxf, fy = yf - lyf, fz = zf - lzf;
    int ix = (int)lxf, iy = (int)lyf, iz = (int)lzf;
    float wv = feat[i] * scale;
    float wx[2] = {1.f - fx, fx}, wy[2] = {1.f - fy, fy}, wz[2] = {1.f - fz, fz};
#pragma unroll
    for (int dz = 0; dz < 2; ++dz) {
        int z2 = iz + dz; if ((unsigned)z2 >= (unsigned)V) continue;
#pragma unroll
        for (int dy = 0; dy < 2; ++dy) {
            int y2 = iy + dy; if ((unsigned)y2 >= (unsigned)V) continue;
            float wzy = wz[dz] * wy[dy] * wv;
            int base = (z2 * V + y2) * V;
#pragma unroll
            for (int dx = 0; dx < 2; ++dx) {
                int x2 = ix + dx; if ((unsigned)x2 >= (unsigned)V) continue;
                unsafeAtomicAdd(dst + base + x2, wzy * wx[dx]);
            }
        }
    }
}

extern "C" void kernel_launch(void* const* d_in, const int* in_sizes, int n_in,
                              void* d_out, int out_size, void* d_ws, size_t ws_size,
                              hipStream_t stream) {
    const float* pts  = (const float*)d_in[0];
    const float* feat = (const float*)d_in[1];
    float* out = (float*)d_out;

    if (ws_size < WS_REQ) {
        int n4 = out_size / 4;
        zero_f4<<<(n4 + 255) / 256, 256, 0, stream>>>((float4*)out, n4);
        splat_direct<<<(NPTS + 255) / 256, 256, 0, stream>>>(pts, feat, out);
        return;
    }

    char* ws = (char*)d_ws;
    unsigned long long* payA = (unsigned long long*)(ws + A_OFF);
    unsigned* partials       = (unsigned*)(ws + P_OFF);
    unsigned* totals         = (unsigned*)(ws + T_OFF);
    unsigned* bases          = (unsigned*)(ws + B_OFF);
    float* payB              = (float*)(ws + F_OFF);
    float* halo              = (float*)(ws + H_OFF);

    count_k  <<<NBLK, 256, 0, stream>>>(pts, partials);
    totals_k <<<NBINS / 256, 256, 0, stream>>>(partials, totals);
    scan_k   <<<1, 1024, 0, stream>>>(totals, bases);
    offsets_k<<<NBINS / 256, 256, 0, stream>>>(partials, bases);
    scatter_k<<<NBLK, 256, 0, stream>>>(pts, feat, partials, payA, payB);
    splat_cells_k<<<NCELLS, 256, 0, stream>>>(payA, payB, bases, out, halo);
    halo_k   <<<(1u << 25) / 256, 256, 0, stream>>>(halo, out);
}

// Round 4
// 1291.271 us; speedup vs baseline: 3.8837x; 1.2052x over previous
//
#include <hip/hip_runtime.h>
#include <hip/hip_fp16.h>

// NeRV trilinear splat, v3 (resubmit — round-3 bench failed on infra, not kernel).
// Round-2 evidence: scatter_k bound by scattered partial-sector HBM writes
// (WRITE_SIZE = 64 B/point across two arrays, ~44 G sector-RMW/s). v3 packs
// each point into ONE 8-byte record (cell-local 11-bit-frac coords + f16
// weight), uses 32x16x16 cells (4096 bins -> run length ~3 records), and
// halves splat payload reads.

#define V 256
#define VOLSZ (V * V * V)              // 16,777,216
#define LOG2P 22
#define NPTS (3 << LOG2P)              // 12,582,912
#define NBLK 1024                      // blocks for count/scatter
#define PPB (NPTS / NBLK)              // 12,288
#define PITER (PPB / 256)              // 48
#define NBINS 4096                     // 2 groups * 2048 cells (32x16x16 voxels)
#define NCPG 2048                      // cells per group: 8 x 16 x 16
// tile: (x 33) x (y 17) x (z 17), x fastest
#define TX 33
#define TXY (TX * 17)                  // 561
#define TILE3 (TXY * 17)               // 9537 floats = 38.1 KB
#define HALO 1345                      // 9537 - 32*16*16

// workspace layout (bytes)
#define R_OFF 0ULL
#define R_BYTES (8ULL * NPTS)                       // packed records (100.7 MB)
#define P_OFF (R_OFF + R_BYTES)
#define P_BYTES (4ULL * NBLK * NBINS)               // per-block histograms (16 MB)
#define T_OFF (P_OFF + P_BYTES)
#define T_BYTES (4ULL * NBINS)
#define B_OFF (T_OFF + T_BYTES)
#define B_BYTES (4ULL * (NBINS + 1) + 28)
#define H_OFF (B_OFF + B_BYTES)
#define H_BYTES (4ULL * NBINS * HALO)               // halo side buffer (22 MB)
#define WS_REQ (H_OFF + H_BYTES)                    // ~139 MB

// fixed-point: voxel coord * 2048 (11-bit fraction), 19 bits total.
// cell: cx = X>>16 (32-voxel), cy = Y>>15, cz = Z>>15 (16-voxel).
__device__ __forceinline__ void point_to_bin(float x, float y, float z,
                                             unsigned& X, unsigned& Y, unsigned& Z,
                                             int& cell) {
    float xf = (x + 1.f) * 127.5f;   // [0, 255]
    float yf = (y + 1.f) * 127.5f;
    float zf = (z + 1.f) * 127.5f;
    X = (unsigned)(int)(xf * 2048.0f);
    Y = (unsigned)(int)(yf * 2048.0f);
    Z = (unsigned)(int)(zf * 2048.0f);
    int cx = (int)(X >> 16), cy = (int)(Y >> 15), cz = (int)(Z >> 15);
    cell = (cz << 7) | (cy << 3) | cx;            // [0, 2048)
}

// ---------------- pass 1: per-block histogram ----------------
__global__ __launch_bounds__(256)
void count_k(const float* __restrict__ pts, unsigned* __restrict__ partials) {
    __shared__ unsigned hist[NBINS];
    for (int j = threadIdx.x; j < NBINS; j += 256) hist[j] = 0u;
    __syncthreads();
    int b = blockIdx.x;
    long long base = (long long)b * PPB;
#pragma unroll 4
    for (int k = 0; k < PITER; ++k) {
        long long i = base + threadIdx.x + k * 256;
        int view = (int)(i >> LOG2P);
        const float* pp = pts + i * 3;
        unsigned X, Y, Z; int cell;
        point_to_bin(pp[0], pp[1], pp[2], X, Y, Z, cell);
        int bin = ((view < 2) ? 0 : NCPG) + cell;
        atomicAdd(&hist[bin], 1u);
    }
    __syncthreads();
    for (int j = threadIdx.x; j < NBINS; j += 256)
        partials[(size_t)b * NBINS + j] = hist[j];
}

// ---------------- pass 2a: bin totals ----------------
__global__ __launch_bounds__(256)
void totals_k(const unsigned* __restrict__ partials, unsigned* __restrict__ totals) {
    int bin = blockIdx.x * 256 + threadIdx.x;
    unsigned s = 0;
#pragma unroll 8
    for (int k = 0; k < NBLK; ++k) s += partials[(size_t)k * NBINS + bin];
    totals[bin] = s;
}

// ---------------- pass 2b: exclusive scan of totals -> bases[NBINS+1] ----------------
__global__ __launch_bounds__(1024)
void scan_k(const unsigned* __restrict__ totals, unsigned* __restrict__ bases) {
    __shared__ unsigned chunk[1024];
    int t = threadIdx.x;
    unsigned v[NBINS / 1024]; unsigned run = 0;
#pragma unroll
    for (int j = 0; j < NBINS / 1024; ++j) { v[j] = totals[t * (NBINS / 1024) + j]; run += v[j]; }
    chunk[t] = run;
    __syncthreads();
    for (int off = 1; off < 1024; off <<= 1) {
        unsigned add = (t >= off) ? chunk[t - off] : 0u;
        __syncthreads();
        chunk[t] += add;
        __syncthreads();
    }
    unsigned excl = (t == 0) ? 0u : chunk[t - 1];
    unsigned r = excl;
    if (t == 0) bases[0] = 0u;
#pragma unroll
    for (int j = 0; j < NBINS / 1024; ++j) { r += v[j]; bases[t * (NBINS / 1024) + 1 + j] = r; }
}

// ---------------- pass 2c: per-(block,bin) start offsets, in place ----------------
__global__ __launch_bounds__(256)
void offsets_k(unsigned* __restrict__ partials, const unsigned* __restrict__ bases) {
    int bin = blockIdx.x * 256 + threadIdx.x;
    unsigned run = bases[bin];
#pragma unroll 8
    for (int k = 0; k < NBLK; ++k) {
        unsigned c = partials[(size_t)k * NBINS + bin];
        partials[(size_t)k * NBINS + bin] = run;
        run += c;
    }
}

// ---------------- pass 3: scatter points into bin-sorted 8B records ----------------
// record: lo = lx16 | ly15<<16 (1 spare bit); hi = lz15 | f16<<16
__global__ __launch_bounds__(256)
void scatter_k(const float* __restrict__ pts, const float* __restrict__ feat,
               const unsigned* __restrict__ offsets,
               unsigned long long* __restrict__ recs) {
    __shared__ unsigned cur[NBINS];
    int b = blockIdx.x;
    for (int j = threadIdx.x; j < NBINS; j += 256)
        cur[j] = offsets[(size_t)b * NBINS + j];
    __syncthreads();
    long long base = (long long)b * PPB;
#pragma unroll 2
    for (int k = 0; k < PITER; ++k) {
        long long i = base + threadIdx.x + k * 256;
        int view = (int)(i >> LOG2P);
        const float* pp = pts + i * 3;
        unsigned X, Y, Z; int cell;
        point_to_bin(pp[0], pp[1], pp[2], X, Y, Z, cell);
        int bin = ((view < 2) ? 0 : NCPG) + cell;
        float wv = feat[i] * ((view < 2) ? 0.5f : 1.0f);
        unsigned hw = __half_as_ushort(__float2half(wv));
        unsigned lo = (X & 0xFFFFu) | ((Y & 0x7FFFu) << 16);
        unsigned hi = (Z & 0x7FFFu) | (hw << 16);
        unsigned slot = atomicAdd(&cur[bin], 1u);
        recs[slot] = (unsigned long long)lo | ((unsigned long long)hi << 32);
    }
}

// ---------------- pass 4: per-cell splat into LDS tile, plain flush ----------------
__global__ __launch_bounds__(256)
void splat_cells_k(const unsigned long long* __restrict__ recs,
                   const unsigned* __restrict__ bases,
                   float* __restrict__ out, float* __restrict__ halo) {
    __shared__ float tile[TILE3];
    for (int j = threadIdx.x; j < TILE3; j += 256) tile[j] = 0.f;
    __syncthreads();
    int bid = blockIdx.x;
    unsigned s = bases[bid], e = bases[bid + 1];
    for (unsigned i = s + threadIdx.x; i < e; i += 256) {
        unsigned long long a = recs[i];
        unsigned lo = (unsigned)a, hi = (unsigned)(a >> 32);
        unsigned lxf = lo & 0xFFFFu;           // 5.11
        unsigned lyf = (lo >> 16) & 0x7FFFu;   // 4.11
        unsigned lzf = hi & 0x7FFFu;           // 4.11
        float w = __half2float(__ushort_as_half((unsigned short)(hi >> 16)));
        int lx = lxf >> 11, ly = lyf >> 11, lz = lzf >> 11;
        float fx = (lxf & 2047u) * (1.f / 2048.f);
        float fy = (lyf & 2047u) * (1.f / 2048.f);
        float fz = (lzf & 2047u) * (1.f / 2048.f);
        float wx0 = 1.f - fx, wy0 = 1.f - fy, wz0 = 1.f - fz;
        int t0 = (lz * 17 + ly) * TX + lx;
        float w00 = w * wz0 * wy0, w01 = w * wz0 * fy;
        float w10 = w * fz * wy0,  w11 = w * fz * fy;
        atomicAdd(&tile[t0],               w00 * wx0);
        atomicAdd(&tile[t0 + 1],           w00 * fx);
        atomicAdd(&tile[t0 + TX],          w01 * wx0);
        atomicAdd(&tile[t0 + TX + 1],      w01 * fx);
        atomicAdd(&tile[t0 + TXY],         w10 * wx0);
        atomicAdd(&tile[t0 + TXY + 1],     w10 * fx);
        atomicAdd(&tile[t0 + TXY + TX],    w11 * wx0);
        atomicAdd(&tile[t0 + TXY + TX + 1], w11 * fx);
    }
    __syncthreads();
    int g = bid >> 11, cc = bid & (NCPG - 1);
    int cx = cc & 7, cy = (cc >> 3) & 15, cz = cc >> 7;
    int ox = cx * 32, oy = cy * 16, oz = cz * 16;
    size_t obase = (size_t)g * VOLSZ;
    for (int idx = threadIdx.x; idx < TILE3; idx += 256) {
        int lz = idx / TXY;
        int r = idx - lz * TXY;
        int ly = r / TX;
        int lx = r - ly * TX;
        float val = tile[idx];
        if (lx < 32 && ly < 16 && lz < 16) {
            out[obase + ((size_t)(oz + lz) * V + (oy + ly)) * V + (ox + lx)] = val;
        } else {
            int h;
            if (lx == 32)      h = ly * 17 + lz;              // 17*17 = 289
            else if (ly == 16) h = 289 + lx * 17 + lz;        // 32*17 = 544
            else               h = 833 + lx * 16 + ly;        // 32*16 = 512
            halo[(size_t)bid * HALO + h] = val;
        }
    }
}

// ---------------- pass 5: add halo contributions on cell-boundary planes ----------------
__device__ __forceinline__ int hidx(int px, int py, int pz) {
    if (px == 32) return py * 17 + pz;
    if (py == 16) return 289 + px * 17 + pz;
    return 833 + px * 16 + py;
}

__global__ __launch_bounds__(256)
void halo_k(const float* __restrict__ halo, float* __restrict__ out) {
    unsigned tid = blockIdx.x * 256 + threadIdx.x;   // 2^25 threads
    unsigned g = tid >> 24;
    unsigned v = tid & 0xFFFFFFu;
    int vx = v & 255, vy = (v >> 8) & 255, vz = v >> 16;
    int lx = vx & 31, ly = vy & 15, lz = vz & 15;
    int cx = vx >> 5, cy = vy >> 4, cz = vz >> 4;
    bool ax = (lx == 0) && (cx > 0);
    bool ay = (ly == 0) && (cy > 0);
    bool az = (lz == 0) && (cz > 0);
    if (!(ax || ay || az)) return;
    auto cellBase = [&](int ccx, int ccy, int ccz) {
        return (size_t)((g << 11) | (ccz << 7) | (ccy << 3) | ccx) * HALO;
    };
    float acc = 0.f;
    if (ax)             acc += halo[cellBase(cx - 1, cy, cz) + hidx(32, ly, lz)];
    if (ay)             acc += halo[cellBase(cx, cy - 1, cz) + hidx(lx, 16, lz)];
    if (az)             acc += halo[cellBase(cx, cy, cz - 1) + hidx(lx, ly, 16)];
    if (ax && ay)       acc += halo[cellBase(cx - 1, cy - 1, cz) + hidx(32, 16, lz)];
    if (ax && az)       acc += halo[cellBase(cx - 1, cy, cz - 1) + hidx(32, ly, 16)];
    if (ay && az)       acc += halo[cellBase(cx, cy - 1, cz - 1) + hidx(lx, 16, 16)];
    if (ax && ay && az) acc += halo[cellBase(cx - 1, cy - 1, cz - 1) + hidx(32, 16, 16)];
    out[(size_t)g * VOLSZ + v] += acc;
}

// ---------------- fallback (ws too small): direct atomic path ----------------
__global__ __launch_bounds__(256)
void zero_f4(float4* __restrict__ p, int n4) {
    int i = blockIdx.x * blockDim.x + threadIdx.x;
    if (i < n4) p[i] = make_float4(0.f, 0.f, 0.f, 0.f);
}

__global__ __launch_bounds__(256)
void splat_direct(const float* __restrict__ pts, const float* __restrict__ feat,
                  float* __restrict__ out) {
    int i = blockIdx.x * blockDim.x + threadIdx.x;
    if (i >= NPTS) return;
    int b = i >> LOG2P;
    const float* pp = pts + (long long)i * 3;
    float scale = (b < 2) ? 0.5f : 1.0f;
    float* dst = out + ((b < 2) ? 0 : VOLSZ);
    float xf = (pp[0] + 1.f) * 127.5f, yf = (pp[1] + 1.f) * 127.5f, zf = (pp[2] + 1.f) * 127.5f;
    float lxf = floorf(xf), lyf = floorf(yf), lzf = floorf(zf);
    float fx = xf - lxf, fy = yf - lyf, fz = zf - lzf;
    int ix = (int)lxf, iy = (int)lyf, iz = (int)lzf;
    float wv = feat[i] * scale;
    float wx[2] = {1.f - fx, fx}, wy[2] = {1.f - fy, fy}, wz[2] = {1.f - fz, fz};
#pragma unroll
    for (int dz = 0; dz < 2; ++dz) {
        int z2 = iz + dz; if ((unsigned)z2 >= (unsigned)V) continue;
#pragma unroll
        for (int dy = 0; dy < 2; ++dy) {
            int y2 = iy + dy; if ((unsigned)y2 >= (unsigned)V) continue;
            float wzy = wz[dz] * wy[dy] * wv;
            int base = (z2 * V + y2) * V;
#pragma unroll
            for (int dx = 0; dx < 2; ++dx) {
                int x2 = ix + dx; if ((unsigned)x2 >= (unsigned)V) continue;
                unsafeAtomicAdd(dst + base + x2, wzy * wx[dx]);
            }
        }
    }
}

extern "C" void kernel_launch(void* const* d_in, const int* in_sizes, int n_in,
                              void* d_out, int out_size, void* d_ws, size_t ws_size,
                              hipStream_t stream) {
    const float* pts  = (const float*)d_in[0];
    const float* feat = (const float*)d_in[1];
    float* out = (float*)d_out;

    if (ws_size < WS_REQ) {
        int n4 = out_size / 4;
        zero_f4<<<(n4 + 255) / 256, 256, 0, stream>>>((float4*)out, n4);
        splat_direct<<<(NPTS + 255) / 256, 256, 0, stream>>>(pts, feat, out);
        return;
    }

    char* ws = (char*)d_ws;
    unsigned long long* recs = (unsigned long long*)(ws + R_OFF);
    unsigned* partials       = (unsigned*)(ws + P_OFF);
    unsigned* totals         = (unsigned*)(ws + T_OFF);
    unsigned* bases          = (unsigned*)(ws + B_OFF);
    float* halo              = (float*)(ws + H_OFF);

    count_k  <<<NBLK, 256, 0, stream>>>(pts, partials);
    totals_k <<<NBINS / 256, 256, 0, stream>>>(partials, totals);
    scan_k   <<<1, 1024, 0, stream>>>(totals, bases);
    offsets_k<<<NBINS / 256, 256, 0, stream>>>(partials, bases);
    scatter_k<<<NBLK, 256, 0, stream>>>(pts, feat, partials, recs);
    splat_cells_k<<<NBINS, 256, 0, stream>>>(recs, bases, out, halo);
    halo_k   <<<(1u << 25) / 256, 256, 0, stream>>>(halo, out);
}